// Round 1
// baseline (155.613 us; speedup 1.0000x reference)
//
#include <hip/hip_runtime.h>

// ROI Align fp32, B=2 C=256 H=W=100, K ROIs, PH=PW=7, SR=2, scale=0.125
// One wave per (k, 8-channel group); lane = output bin (49 of 64 active).
// Weights/offsets computed once per lane, reused across 8 channels.

#define ROI_PH 7
#define ROI_PW 7
#define ROI_NBIN 49
#define ROI_SR 2
#define ROI_SCALE 0.125f

constexpr int kC = 256;
constexpr int kH = 100;
constexpr int kW = 100;
constexpr int kPlane = kH * kW;   // 10000
constexpr int kCPW = 8;           // channels per wave
constexpr int kWPK = kC / kCPW;   // 32 waves per roi

__global__ __launch_bounds__(256) void roi_align_fwd(
    const float* __restrict__ feat,
    const float* __restrict__ rois,
    float* __restrict__ out,
    int K)
{
    const int lane = threadIdx.x & 63;
    const int wave = threadIdx.x >> 6;
    const int wg   = blockIdx.x * 4 + wave;          // global wave id
    int k  = wg >> 5;                                // wg / kWPK
    int cg = wg & (kWPK - 1);
    if (k >= K) return;

    // force wave-uniform scalars so roi loads become s_load and the
    // gather base stays in SGPRs (compiler can't prove tid>>6 uniform)
    k  = __builtin_amdgcn_readfirstlane(k);
    cg = __builtin_amdgcn_readfirstlane(cg);

    const bool active = lane < ROI_NBIN;
    const int  bin = active ? lane : (ROI_NBIN - 1);
    const int  ph = bin / ROI_PW;
    const int  pw = bin - ph * ROI_PW;

    // ROI params (wave-uniform address -> scalar loads)
    const float* r = rois + (size_t)k * 5;
    const int   bidx = (int)r[0];
    const float x1 = r[1] * ROI_SCALE;
    const float y1 = r[2] * ROI_SCALE;
    const float x2 = r[3] * ROI_SCALE;
    const float y2 = r[4] * ROI_SCALE;
    const float roi_w = fmaxf(x2 - x1, 1.0f);
    const float roi_h = fmaxf(y2 - y1, 1.0f);
    const float bw = roi_w * (1.0f / ROI_PW);
    const float bh = roi_h * (1.0f / ROI_PH);

    // per-bin sample weights & offsets (validity and 1/4 mean folded in)
    float wgt[4][4];
    int   off[4][4];
#pragma unroll
    for (int sy = 0; sy < 2; ++sy) {
#pragma unroll
        for (int sx = 0; sx < 2; ++sx) {
            const int s = sy * 2 + sx;
            const float gy = y1 + ((float)(2 * ph + sy) + 0.5f) * (bh * 0.5f);
            const float gx = x1 + ((float)(2 * pw + sx) + 0.5f) * (bw * 0.5f);
            const float vy = (gy >= -1.0f && gy <= (float)kH) ? 1.0f : 0.0f;
            const float vx = (gx >= -1.0f && gx <= (float)kW) ? 1.0f : 0.0f;
            const float yc = fminf(fmaxf(gy, 0.0f), (float)(kH - 1));
            const float xc = fminf(fmaxf(gx, 0.0f), (float)(kW - 1));
            const int y0 = (int)floorf(yc);
            const int x0 = (int)floorf(xc);
            const int y1i = min(y0 + 1, kH - 1);
            const int x1i = min(x0 + 1, kW - 1);
            const float ly = yc - (float)y0;
            const float lx = xc - (float)x0;
            const float hy = 1.0f - ly;
            const float hx = 1.0f - lx;
            const float vm = vy * vx * 0.25f;
            wgt[s][0] = hy * hx * vm;
            wgt[s][1] = hy * lx * vm;
            wgt[s][2] = ly * hx * vm;
            wgt[s][3] = ly * lx * vm;
            off[s][0] = y0  * kW + x0;
            off[s][1] = y0  * kW + x1i;
            off[s][2] = y1i * kW + x0;
            off[s][3] = y1i * kW + x1i;
        }
    }

    const float* plane0 = feat + ((size_t)bidx * kC + (size_t)cg * kCPW) * kPlane;
    float* outp = out + (size_t)k * kC * ROI_NBIN + (size_t)cg * kCPW * ROI_NBIN + bin;

#pragma unroll
    for (int ci = 0; ci < kCPW; ++ci) {
        const float* __restrict__ p = plane0 + (size_t)ci * kPlane;
        float acc = 0.0f;
#pragma unroll
        for (int s = 0; s < 4; ++s) {
            acc += wgt[s][0] * p[off[s][0]];
            acc += wgt[s][1] * p[off[s][1]];
            acc += wgt[s][2] * p[off[s][2]];
            acc += wgt[s][3] * p[off[s][3]];
        }
        if (active) outp[ci * ROI_NBIN] = acc;
    }
}

extern "C" void kernel_launch(void* const* d_in, const int* in_sizes, int n_in,
                              void* d_out, int out_size, void* d_ws, size_t ws_size,
                              hipStream_t stream) {
    const float* feat = (const float*)d_in[0];
    const float* rois = (const float*)d_in[1];
    float* out = (float*)d_out;
    const int K = in_sizes[1] / 5;           // 1000

    const int total_waves = K * kWPK;        // 32000
    const int blocks = (total_waves + 3) / 4; // 4 waves per block of 256
    roi_align_fwd<<<blocks, 256, 0, stream>>>(feat, rois, out, K);
}

// Round 2
// 45.312 us; speedup vs baseline: 3.4343x; 3.4343x over previous
//
#include <hip/hip_runtime.h>

// ROI Align fp32, B=2 C=256 H=W=100, K ROIs, PH=PW=7, SR=2, scale=0.125
// One wave per (k, 8-channel group); lane = output bin (49 of 64 active).
//
// Key trick: roi_w,roi_h <= 25 feature px => bin_w/2 < 2 px, so all 16
// bilinear taps of a bin's 2x2 samples fall in ONE 4x4 pixel window.
// Weights are separable: wy[4] (x) wx[4] built once per lane, then each
// channel costs 4x global_load_dwordx4 + 16 FMAs.

#define ROI_PH 7
#define ROI_PW 7
#define ROI_NBIN 49
#define ROI_SCALE 0.125f

constexpr int kC = 256;
constexpr int kH = 100;
constexpr int kW = 100;
constexpr int kPlane = kH * kW;   // 10000
constexpr int kCPW = 8;           // channels per wave
constexpr int kWPK = kC / kCPW;   // 32 waves per roi

typedef float f32x4 __attribute__((ext_vector_type(4)));

// 16B load with only 4B alignment guarantee; compiler emits
// global_load_dwordx4 (flat/global needs dword alignment only).
__device__ inline f32x4 ld4(const float* p) {
    f32x4 v;
    __builtin_memcpy(&v, p, 16);
    return v;
}

// Build the 4-slot tap-scatter weights for one axis.
// taps: (i0, w0h),(i0+1->i1, w0l) from sample0; (j0, w1h),(j1, w1l) from sample1.
__device__ inline void axis_weights(float g0, float g1, int dim,
                                    int& base, float w[4]) {
    const float v0 = (g0 >= -1.0f && g0 <= (float)dim) ? 1.0f : 0.0f;
    const float v1 = (g1 >= -1.0f && g1 <= (float)dim) ? 1.0f : 0.0f;
    const float c0 = fminf(fmaxf(g0, 0.0f), (float)(dim - 1));
    const float c1 = fminf(fmaxf(g1, 0.0f), (float)(dim - 1));
    const int i0 = (int)floorf(c0);
    const int j0 = (int)floorf(c1);
    const int i1 = min(i0 + 1, dim - 1);
    const int j1 = min(j0 + 1, dim - 1);
    const float l0 = c0 - (float)i0;
    const float l1 = c1 - (float)j0;
    const float tw0 = (1.0f - l0) * v0;   // at i0
    const float tw1 = l0 * v0;            // at i1
    const float tw2 = (1.0f - l1) * v1;   // at j0
    const float tw3 = l1 * v1;            // at j1
    base = min(i0, dim - 4);              // window [base, base+3] covers all taps
#pragma unroll
    for (int d = 0; d < 4; ++d) {
        const int idx = base + d;
        float acc = 0.0f;
        acc += (i0 == idx) ? tw0 : 0.0f;
        acc += (i1 == idx) ? tw1 : 0.0f;
        acc += (j0 == idx) ? tw2 : 0.0f;
        acc += (j1 == idx) ? tw3 : 0.0f;
        w[d] = acc;
    }
}

__global__ __launch_bounds__(256) void roi_align_fwd(
    const float* __restrict__ feat,
    const float* __restrict__ rois,
    float* __restrict__ out,
    int K)
{
    const int lane = threadIdx.x & 63;
    const int wave = threadIdx.x >> 6;
    const int wg   = blockIdx.x * 4 + wave;
    int k  = wg >> 5;
    int cg = wg & (kWPK - 1);
    if (k >= K) return;

    k  = __builtin_amdgcn_readfirstlane(k);
    cg = __builtin_amdgcn_readfirstlane(cg);

    const bool active = lane < ROI_NBIN;
    const int  bin = active ? lane : (ROI_NBIN - 1);
    const int  ph = bin / ROI_PW;
    const int  pw = bin - ph * ROI_PW;

    // ROI params (wave-uniform -> scalar loads)
    const float* r = rois + (size_t)k * 5;
    const int   bidx = (int)r[0];
    const float x1 = r[1] * ROI_SCALE;
    const float y1 = r[2] * ROI_SCALE;
    const float x2 = r[3] * ROI_SCALE;
    const float y2 = r[4] * ROI_SCALE;
    const float bw2 = fmaxf(x2 - x1, 1.0f) * (0.5f / ROI_PW);  // bin_w/2
    const float bh2 = fmaxf(y2 - y1, 1.0f) * (0.5f / ROI_PH);  // bin_h/2

    // the two sample coords per axis for this bin
    const float gy0 = y1 + ((float)(2 * ph) + 0.5f) * bh2;
    const float gy1 = y1 + ((float)(2 * ph) + 1.5f) * bh2;
    const float gx0 = x1 + ((float)(2 * pw) + 0.5f) * bw2;
    const float gx1 = x1 + ((float)(2 * pw) + 1.5f) * bw2;

    int ybase, xbase;
    float wy[4], wx[4];
    axis_weights(gy0, gy1, kH, ybase, wy);
    axis_weights(gx0, gx1, kW, xbase, wx);

    // 4x4 combined weights, 1/4 mean folded in
    float wgt[4][4];
#pragma unroll
    for (int dy = 0; dy < 4; ++dy) {
        const float wyq = wy[dy] * 0.25f;
#pragma unroll
        for (int dx = 0; dx < 4; ++dx) wgt[dy][dx] = wyq * wx[dx];
    }

    const float* plane0 = feat + ((size_t)bidx * kC + (size_t)cg * kCPW) * kPlane
                               + (size_t)(ybase * kW + xbase);
    float* outp = out + ((size_t)k * kC + (size_t)cg * kCPW) * ROI_NBIN + bin;

#pragma unroll
    for (int ci = 0; ci < kCPW; ++ci) {
        const float* __restrict__ p = plane0 + (size_t)ci * kPlane;
        const f32x4 r0 = ld4(p);
        const f32x4 r1 = ld4(p + kW);
        const f32x4 r2 = ld4(p + 2 * kW);
        const f32x4 r3 = ld4(p + 3 * kW);
        float acc = 0.0f;
#pragma unroll
        for (int dx = 0; dx < 4; ++dx) acc += wgt[0][dx] * r0[dx];
#pragma unroll
        for (int dx = 0; dx < 4; ++dx) acc += wgt[1][dx] * r1[dx];
#pragma unroll
        for (int dx = 0; dx < 4; ++dx) acc += wgt[2][dx] * r2[dx];
#pragma unroll
        for (int dx = 0; dx < 4; ++dx) acc += wgt[3][dx] * r3[dx];
        if (active) outp[ci * ROI_NBIN] = acc;
    }
}

extern "C" void kernel_launch(void* const* d_in, const int* in_sizes, int n_in,
                              void* d_out, int out_size, void* d_ws, size_t ws_size,
                              hipStream_t stream) {
    const float* feat = (const float*)d_in[0];
    const float* rois = (const float*)d_in[1];
    float* out = (float*)d_out;
    const int K = in_sizes[1] / 5;            // 1000

    const int total_waves = K * kWPK;         // 32000
    const int blocks = (total_waves + 3) / 4; // 4 waves of 64 per block
    roi_align_fwd<<<blocks, 256, 0, stream>>>(feat, rois, out, K);
}

// Round 3
// 45.046 us; speedup vs baseline: 3.4545x; 1.0059x over previous
//
#include <hip/hip_runtime.h>

// ROI Align fp32, B=2 C=256 H=W=100, K ROIs, PH=PW=7, SR=2, scale=0.125
// One wave per (k, 8-channel group); lane = output bin (49 of 64 active).
// All 16 bilinear taps of a bin fall in one 4x4 window (roi_w<=25 => bin_w/2<2).
// Round 3: software-pipelined channel loop (4 batches x 2 channels, 2-deep
// prefetch) to raise memory-level parallelism; VGPR budget 128 (4 waves/EU).

#define ROI_PH 7
#define ROI_PW 7
#define ROI_NBIN 49
#define ROI_SCALE 0.125f

constexpr int kC = 256;
constexpr int kH = 100;
constexpr int kW = 100;
constexpr int kPlane = kH * kW;   // 10000
constexpr int kCPW = 8;           // channels per wave
constexpr int kWPK = kC / kCPW;   // 32 waves per roi

typedef float f32x4 __attribute__((ext_vector_type(4)));

__device__ inline f32x4 ld4(const float* p) {
    f32x4 v;
    __builtin_memcpy(&v, p, 16);   // global_load_dwordx4 (4B-aligned ok)
    return v;
}

// 4-slot tap-scatter weights for one axis (two samples, bilinear each).
__device__ inline void axis_weights(float g0, float g1, int dim,
                                    int& base, float w[4]) {
    const float v0 = (g0 >= -1.0f && g0 <= (float)dim) ? 1.0f : 0.0f;
    const float v1 = (g1 >= -1.0f && g1 <= (float)dim) ? 1.0f : 0.0f;
    const float c0 = fminf(fmaxf(g0, 0.0f), (float)(dim - 1));
    const float c1 = fminf(fmaxf(g1, 0.0f), (float)(dim - 1));
    const int i0 = (int)floorf(c0);
    const int j0 = (int)floorf(c1);
    const int i1 = min(i0 + 1, dim - 1);
    const int j1 = min(j0 + 1, dim - 1);
    const float l0 = c0 - (float)i0;
    const float l1 = c1 - (float)j0;
    const float tw0 = (1.0f - l0) * v0;
    const float tw1 = l0 * v0;
    const float tw2 = (1.0f - l1) * v1;
    const float tw3 = l1 * v1;
    base = min(i0, dim - 4);
#pragma unroll
    for (int d = 0; d < 4; ++d) {
        const int idx = base + d;
        float acc = 0.0f;
        acc += (i0 == idx) ? tw0 : 0.0f;
        acc += (i1 == idx) ? tw1 : 0.0f;
        acc += (j0 == idx) ? tw2 : 0.0f;
        acc += (j1 == idx) ? tw3 : 0.0f;
        w[d] = acc;
    }
}

__device__ inline void load_pair(f32x4 (&dst)[2][4], const float* plane0, int b) {
#pragma unroll
    for (int c = 0; c < 2; ++c) {
        const float* p = plane0 + (size_t)(b * 2 + c) * kPlane;
        dst[c][0] = ld4(p);
        dst[c][1] = ld4(p + kW);
        dst[c][2] = ld4(p + 2 * kW);
        dst[c][3] = ld4(p + 3 * kW);
    }
}

__device__ inline void compute_pair(const f32x4 (&src)[2][4],
                                    const float (&wgt)[4][4],
                                    float* outp, int b, bool active) {
#pragma unroll
    for (int c = 0; c < 2; ++c) {
        float acc = 0.0f;
#pragma unroll
        for (int dy = 0; dy < 4; ++dy)
#pragma unroll
            for (int dx = 0; dx < 4; ++dx)
                acc += wgt[dy][dx] * src[c][dy][dx];
        if (active) outp[(b * 2 + c) * ROI_NBIN] = acc;
    }
}

__global__ __launch_bounds__(256, 4) void roi_align_fwd(
    const float* __restrict__ feat,
    const float* __restrict__ rois,
    float* __restrict__ out,
    int K)
{
    const int lane = threadIdx.x & 63;
    const int wave = threadIdx.x >> 6;
    const int wg   = blockIdx.x * 4 + wave;
    int k  = wg >> 5;
    int cg = wg & (kWPK - 1);
    if (k >= K) return;

    k  = __builtin_amdgcn_readfirstlane(k);
    cg = __builtin_amdgcn_readfirstlane(cg);

    const bool active = lane < ROI_NBIN;
    const int  bin = active ? lane : (ROI_NBIN - 1);
    const int  ph = bin / ROI_PW;
    const int  pw = bin - ph * ROI_PW;

    const float* r = rois + (size_t)k * 5;
    const int   bidx = (int)r[0];
    const float x1 = r[1] * ROI_SCALE;
    const float y1 = r[2] * ROI_SCALE;
    const float x2 = r[3] * ROI_SCALE;
    const float y2 = r[4] * ROI_SCALE;
    const float bw2 = fmaxf(x2 - x1, 1.0f) * (0.5f / ROI_PW);
    const float bh2 = fmaxf(y2 - y1, 1.0f) * (0.5f / ROI_PH);

    const float gy0 = y1 + ((float)(2 * ph) + 0.5f) * bh2;
    const float gy1 = y1 + ((float)(2 * ph) + 1.5f) * bh2;
    const float gx0 = x1 + ((float)(2 * pw) + 0.5f) * bw2;
    const float gx1 = x1 + ((float)(2 * pw) + 1.5f) * bw2;

    int ybase, xbase;
    float wy[4], wx[4];
    axis_weights(gy0, gy1, kH, ybase, wy);
    axis_weights(gx0, gx1, kW, xbase, wx);

    float wgt[4][4];
#pragma unroll
    for (int dy = 0; dy < 4; ++dy) {
        const float wyq = wy[dy] * 0.25f;
#pragma unroll
        for (int dx = 0; dx < 4; ++dx) wgt[dy][dx] = wyq * wx[dx];
    }

    const float* plane0 = feat + ((size_t)bidx * kC + (size_t)cg * kCPW) * kPlane
                               + (size_t)(ybase * kW + xbase);
    float* outp = out + ((size_t)k * kC + (size_t)cg * kCPW) * ROI_NBIN + bin;

    // 4 batches x 2 channels, 2-deep software pipeline. All array indices
    // compile-time constant (named buffers) so everything stays in VGPRs.
    f32x4 bufA[2][4], bufB[2][4], bufC[2][4], bufD[2][4];
    load_pair(bufA, plane0, 0);
    load_pair(bufB, plane0, 1);
    load_pair(bufC, plane0, 2);          // issue batch 2 before computing 0
    compute_pair(bufA, wgt, outp, 0, active);
    load_pair(bufD, plane0, 3);
    compute_pair(bufB, wgt, outp, 1, active);
    compute_pair(bufC, wgt, outp, 2, active);
    compute_pair(bufD, wgt, outp, 3, active);
}

extern "C" void kernel_launch(void* const* d_in, const int* in_sizes, int n_in,
                              void* d_out, int out_size, void* d_ws, size_t ws_size,
                              hipStream_t stream) {
    const float* feat = (const float*)d_in[0];
    const float* rois = (const float*)d_in[1];
    float* out = (float*)d_out;
    const int K = in_sizes[1] / 5;            // 1000

    const int total_waves = K * kWPK;         // 32000
    const int blocks = (total_waves + 3) / 4; // 4 waves of 64 per block
    roi_align_fwd<<<blocks, 256, 0, stream>>>(feat, rois, out, K);
}